// Round 8
// baseline (1337.406 us; speedup 1.0000x reference)
//
#include <hip/hip_runtime.h>
#include <math.h>

// Problem dims (fixed): B=2, S=2048 -> TOK=4096 tokens; H=4096; I=11008
#define TOK 4096
#define HD  4096
#define ID  11008

typedef int i32x4 __attribute__((ext_vector_type(4)));
typedef float f32x4v __attribute__((ext_vector_type(4)));
typedef char i8x4v __attribute__((ext_vector_type(4)));

#define GLDS16(g, l) __builtin_amdgcn_global_load_lds( \
    (const __attribute__((address_space(1))) void*)(g), \
    (__attribute__((address_space(3))) void*)(l), 16, 0, 0)

// ---------------------------------------------------------------- convert ---
__global__ void conv_all(const float* __restrict__ x,  char* __restrict__ xq,
                         const float* __restrict__ wg, char* __restrict__ wgq,
                         const float* __restrict__ wu, char* __restrict__ wuq,
                         const float* __restrict__ wd, char* __restrict__ wdq)
{
  const long NX = (long)TOK * HD / 4, NW = (long)ID * HD / 4;
  const long total = NX + 3 * NW;
  const long stride = (long)gridDim.x * blockDim.x;
  for (long i = (long)blockIdx.x * blockDim.x + threadIdx.x; i < total;
       i += stride) {
    const f32x4v* src; i8x4v* dst; long j;
    if (i < NX)               { src = (const f32x4v*)x;  dst = (i8x4v*)xq;  j = i; }
    else if (i < NX + NW)     { src = (const f32x4v*)wg; dst = (i8x4v*)wgq; j = i - NX; }
    else if (i < NX + 2 * NW) { src = (const f32x4v*)wu; dst = (i8x4v*)wuq; j = i - NX - NW; }
    else                      { src = (const f32x4v*)wd; dst = (i8x4v*)wdq; j = i - NX - 2 * NW; }
    f32x4v v = __builtin_nontemporal_load(&src[j]);
    i8x4v o;
    o.x = (char)(int)rintf(v.x);
    o.y = (char)(int)rintf(v.y);
    o.z = (char)(int)rintf(v.z);
    o.w = (char)(int)rintf(v.w);
    dst[j] = o;
  }
}

// ----------------------------------------------------------------- GEMM -----
// out[m,n] = sum_k A[m,k]*B[n,k]  (both K-major int8), i32 accumulate (exact).
//
// R15: R12's 128x128 tile / 3 blocks/CU TLP (proven best) + a MINIMAL 2-deep
// half-tile pipeline.  R7-R12 arithmetic: cadence 1681 cyc/block-tile vs
// demands MFMA 653 / LDS 768 / HBM 24% -- nothing saturated; the gap is the
// stage->syncthreads(vmcnt(0))->compute serialization that drains the JUST-
// ISSUED loads every tile.  Fix: BK 128->64, the two 64-halves ping-pong as
// natural double buffers inside the SAME 32KB (occupancy preserved); stage
// half kh+1 while computing half kh; gate with counted vmcnt(4) (own 4 loads
// of kh landed; kh+1's stay in flight) + raw s_barrier.  Never vmcnt(0)
// mid-loop (T4).  Barrier2 at iter end protects buffer overwrite (all waves'
// reads of buf[kh&1] retired -- compiler's lgkm-before-MFMA guarantees data
// arrival before MFMA issue).
//
// LDS layout per operand: [half][128 rows][64B], row r chunk c stored at
// slot c ^ ((r>>1)&3).  GLDS16 dest offset = tid*16 (linear, wave-uniform
// base + lane*16 OK); source chunk pre-swizzled c = (tid&3)^((tid>>3)&3).
// Fragment read slot = qd ^ ((wr>>1)&3): per 16-lane phase the bank-groups
// (4*wr + qd^((wr>>1)&3)) mod 8 cover all 8 exactly twice -> conflict-free
// (2-way is free, m136).
//
// MODE 0: gate -> ga = silu(acc*gs), store f32, sum|ga| -> sums[0]
// MODE 1: up   -> inter = clip(rint(ga/ga_s))*acc*(ga_s*up_s), store f32,
//                 sum|inter| -> sums[1]
// MODE 2: down -> plain f32 store (exact integers)
template<int MODE>
__global__ __launch_bounds__(256, 3)
void gemm_i8(const char* __restrict__ A,
             const char* __restrict__ Bm,
             int M, int N, int K,
             float* __restrict__ Cout,
             const float* __restrict__ ga_in,
             const float* __restrict__ sc0,
             const float* __restrict__ sc1,
             double* __restrict__ sums,
             long long NN)
{
  __shared__ char As[16384];     // [2][128][64]
  __shared__ char Bs[16384];

  const int tid  = threadIdx.x;
  const int w    = tid >> 6;        // wave 0..3
  const int lane = tid & 63;
  const int wr   = lane & 15;
  const int qd   = lane >> 4;       // 0..3
  const int wm   = (w >> 1) << 6;
  const int wn   = (w & 1) << 6;

  // XCD-aware swizzle (bijection over all (m_tile, n_tile))
  const int L   = blockIdx.y * gridDim.x + blockIdx.x;
  const int xcd = L & 7;
  const int r   = L >> 3;
  const int m0  = (xcd + ((r & 3) << 3)) << 7;
  const int n0  = (r >> 2) << 7;

  i32x4 acc[4][4] = {};

  // staging: thread covers row (tid>>2)+64g, 16B chunk c = slot^((row>>1)&3)
  const int srow = tid >> 2;                      // 0..63
  const int sc   = (tid & 3) ^ ((tid >> 3) & 3);  // pre-swizzled global chunk
  const char* gA = A  + (size_t)(m0 + srow) * K + (sc << 4);
  const char* gB = Bm + (size_t)(n0 + srow) * K + (sc << 4);
  const size_t r64K = (size_t)64 * K;
  char* dA = As + (w << 10);      // + (kh&1)<<13, + 4096 for g=1
  char* dB = Bs + (w << 10);

  // fragment offsets: row*(64B) + swizzled slot
  const int rsw   = (qd ^ ((wr >> 1) & 3)) << 4;
  const int abase = ((wm + wr) << 6) + rsw;
  const int bbase = ((wn + wr) << 6) + rsw;

  const int NH = K >> 6;          // 64-wide K halves

#define STAGE(kh) do { const size_t ko = (size_t)(kh) << 6;                \
    const int hb_ = ((kh) & 1) << 13;                                      \
    GLDS16(gA + ko,        dA + hb_);                                      \
    GLDS16(gA + ko + r64K, dA + hb_ + 4096);                               \
    GLDS16(gB + ko,        dB + hb_);                                      \
    GLDS16(gB + ko + r64K, dB + hb_ + 4096); } while (0)

  STAGE(0);

#pragma unroll 2
  for (int kh = 0; kh < NH; ++kh) {
    if (kh + 1 < NH) {
      STAGE(kh + 1);
      asm volatile("s_waitcnt vmcnt(4)" ::: "memory");  // kh's 4 landed
    } else {
      asm volatile("s_waitcnt vmcnt(0)" ::: "memory");
    }
    __builtin_amdgcn_s_barrier();      // all waves' kh slices visible

    const int hb = (kh & 1) << 13;
    i32x4 af[4], bf[4];
#pragma unroll
    for (int i = 0; i < 4; i++)
      af[i] = *(const i32x4*)(As + hb + abase + (i << 10));
#pragma unroll
    for (int j = 0; j < 4; j++)
      bf[j] = *(const i32x4*)(Bs + hb + bbase + (j << 10));

#pragma unroll
    for (int i = 0; i < 4; i++)
#pragma unroll
      for (int j = 0; j < 4; j++)
        acc[i][j] = __builtin_amdgcn_mfma_i32_16x16x64_i8(af[i], bf[j],
                                                          acc[i][j], 0, 0, 0);
    __builtin_amdgcn_s_barrier();      // reads retired -> buf reusable
  }
#undef STAGE

  // epilogue: C/D layout col = lane&15 (n), row = quad*4 + reg (m)
  double lsum = 0.0;

  if (MODE == 0) {
    const float gs = sc0[0] * sc1[0];
#pragma unroll
    for (int i = 0; i < 4; i++) {
      const int mb = m0 + wm + (i << 4) + (qd << 2);
#pragma unroll
      for (int j = 0; j < 4; j++) {
        const int n = n0 + wn + (j << 4) + wr;
#pragma unroll
        for (int r2 = 0; r2 < 4; r2++) {
          float g = (float)acc[i][j][r2] * gs;
          float s = g / (1.0f + expf(-g));          // silu
          __builtin_nontemporal_store(s, &Cout[(size_t)(mb + r2) * N + n]);
          lsum += (double)fabsf(s);
        }
      }
    }
  } else if (MODE == 1) {
    const float up_s  = sc0[0] * sc1[0];
    const float ga_s  = (float)(sums[0] / (double)NN) + 1e-8f;
    const float combo = ga_s * up_s;
#pragma unroll
    for (int i = 0; i < 4; i++) {
      const int mb = m0 + wm + (i << 4) + (qd << 2);
#pragma unroll
      for (int j = 0; j < 4; j++) {
        const int n = n0 + wn + (j << 4) + wr;
#pragma unroll
        for (int r2 = 0; r2 < 4; r2++) {
          float up = (float)acc[i][j][r2];
          float ga = __builtin_nontemporal_load(
                         &ga_in[(size_t)(mb + r2) * N + n]);
          float gq = fmaxf(-128.0f, fminf(127.0f, rintf(ga / ga_s)));
          float itv = gq * up * combo;              // same assoc as reference
          __builtin_nontemporal_store(itv, &Cout[(size_t)(mb + r2) * N + n]);
          lsum += (double)fabsf(itv);
        }
      }
    }
  } else {
#pragma unroll
    for (int i = 0; i < 4; i++) {
      const int mb = m0 + wm + (i << 4) + (qd << 2);
#pragma unroll
      for (int j = 0; j < 4; j++) {
        const int n = n0 + wn + (j << 4) + wr;
#pragma unroll
        for (int r2 = 0; r2 < 4; r2++)
          __builtin_nontemporal_store((float)acc[i][j][r2],
                                      &Cout[(size_t)(mb + r2) * N + n]);
      }
    }
  }

  if (MODE != 2) {
    for (int off = 32; off; off >>= 1) lsum += __shfl_down(lsum, off, 64);
    double* red = (double*)As;   // reuse LDS: all fragment reads are done
    if (lane == 0) red[w] = lsum;
    __syncthreads();
    if (tid == 0) atomicAdd(&sums[MODE], red[0] + red[1] + red[2] + red[3]);
  }
}

// ------------------------------------------------------------- quantize -----
__global__ void quant_inter(const float* __restrict__ inter,
                            char* __restrict__ outq,
                            const double* __restrict__ sums, long long NN,
                            const float* __restrict__ wsd,
                            float* __restrict__ scalar_out, int n4)
{
  const float is = (float)(sums[1] / (double)NN) + 1e-8f;
  if (blockIdx.x == 0 && threadIdx.x == 0) scalar_out[0] = is * wsd[0];
  int stride = gridDim.x * blockDim.x;
  for (int i = blockIdx.x * blockDim.x + threadIdx.x; i < n4; i += stride) {
    f32x4v v = __builtin_nontemporal_load(&((const f32x4v*)inter)[i]);
    i8x4v o;
    o.x = (char)(int)fmaxf(-128.0f, fminf(127.0f, rintf(v.x / is)));
    o.y = (char)(int)fmaxf(-128.0f, fminf(127.0f, rintf(v.y / is)));
    o.z = (char)(int)fmaxf(-128.0f, fminf(127.0f, rintf(v.z / is)));
    o.w = (char)(int)fmaxf(-128.0f, fminf(127.0f, rintf(v.w / is)));
    ((i8x4v*)outq)[i] = o;                 // cacheable: GEMM2 reads it next
  }
}

// ---------------------------------------------------------------- launch ----
extern "C" void kernel_launch(void* const* d_in, const int* in_sizes, int n_in,
                              void* d_out, int out_size, void* d_ws, size_t ws_size,
                              hipStream_t stream) {
  const float* x        = (const float*)d_in[0];
  const float* x_scale  = (const float*)d_in[1];
  const float* qw_gate  = (const float*)d_in[2];
  const float* ws_gate  = (const float*)d_in[3];
  const float* qw_up    = (const float*)d_in[4];
  const float* ws_up    = (const float*)d_in[5];
  const float* qw_down  = (const float*)d_in[6];
  const float* ws_down  = (const float*)d_in[7];
  float* out = (float*)d_out;

  char* ws = (char*)d_ws;
  double* sums = (double*)ws;                 // [0]=sum|ga| [1]=sum|inter|
  size_t off = 256;
  char* xq     = ws + off; off += (size_t)TOK * HD;
  char* wgq    = ws + off; off += (size_t)ID * HD;
  char* wuq    = ws + off; off += (size_t)ID * HD;
  char* wdq    = ws + off; off += (size_t)HD * ID;
  char* interq = ws + off; off += (size_t)TOK * ID;
  float* ga    = (float*)(ws + off); off += (size_t)TOK * ID * 4;
  float* inter = (float*)(ws + off); off += (size_t)TOK * ID * 4;

  const long long NN = (long long)TOK * ID;

  (void)hipMemsetAsync(sums, 0, 16, stream);

  // all four converts in one launch
  conv_all<<<8192, 256, 0, stream>>>(x, xq, qw_gate, wgq, qw_up, wuq,
                                     qw_down, wdq);

  // gate GEMM + silu + sum|ga|
  gemm_i8<0><<<dim3(ID / 128, TOK / 128), 256, 0, stream>>>(
      xq, wgq, TOK, ID, HD, ga, nullptr, x_scale, ws_gate, sums, NN);

  // up GEMM + inter computation + sum|inter|
  gemm_i8<1><<<dim3(ID / 128, TOK / 128), 256, 0, stream>>>(
      xq, wuq, TOK, ID, HD, inter, ga, x_scale, ws_up, sums, NN);

  // quantize inter -> int8; also write scalar output
  quant_inter<<<8192, 256, 0, stream>>>(inter, interq, sums, NN, ws_down,
                                        out + (size_t)TOK * HD, (int)(NN / 4));

  // down GEMM -> final output (exact integers in f32)
  gemm_i8<2><<<dim3(HD / 128, TOK / 128), 256, 0, stream>>>(
      interq, wdq, TOK, HD, ID, out, nullptr, nullptr, nullptr, sums, NN);
}